// Round 25
// baseline (230.189 us; speedup 1.0000x reference)
//
#include <hip/hip_runtime.h>

#define BATCH 4096
#define NPATCH 16

typedef __attribute__((ext_vector_type(8)))  short  short8;
typedef __attribute__((ext_vector_type(4)))  float  f32x4;
typedef unsigned short ushort_t;

__device__ __forceinline__ ushort_t f2bf(float f) {
    union { float f; unsigned u; } x; x.f = f;
    unsigned r = x.u + 0x7FFFu + ((x.u >> 16) & 1u);
    return (ushort_t)(r >> 16);
}

__device__ __forceinline__ void gload_lds16(const void* g, void* l) {
    __builtin_amdgcn_global_load_lds((const __attribute__((address_space(1))) void*)g,
                                     (__attribute__((address_space(3))) void*)l, 16, 0, 0);
}

// ---------------------------------------------------------------------------
// rank: ids_shuffle (ws) + ids_restore -> target (f32, d_out tail)
// ---------------------------------------------------------------------------
__global__ void rank_kernel(const float* __restrict__ noise,
                            int* __restrict__ ids_shuffle,
                            float* __restrict__ target_out) {
    int n = blockIdx.x * 256 + threadIdx.x;
    if (n >= BATCH) return;
    float v[NPATCH];
#pragma unroll
    for (int i = 0; i < NPATCH; i++) v[i] = noise[n * NPATCH + i];
#pragma unroll
    for (int j = 0; j < NPATCH; j++) {
        int r = 0;
#pragma unroll
        for (int i = 0; i < NPATCH; i++)
            if (v[i] < v[j] || (v[i] == v[j] && i < j)) r++;
        ids_shuffle[n * NPATCH + r] = j;
        target_out[n * NPATCH + j] = (float)r;
    }
}

// ---------------------------------------------------------------------------
// prep_all: ALL weight preps in ONE launch (r18).
// ---------------------------------------------------------------------------
__device__ __forceinline__ void prep_elem(const float* W, ushort_t* WT, int idx,
                                          int IC, int ICP, int KWP) {
    int KP = 3 * KWP * ICP;
    int oc = idx / KP, k = idx % KP;
    int kh = k / (KWP * ICP);
    int kw = (k / ICP) % KWP;
    int ic = k % ICP;
    ushort_t v = 0;
    if (kw < 3 && ic < IC)
        v = f2bf(W[((oc * IC + ic) * 3 + kh) * 3 + kw]);
    WT[idx] = v;
}

__global__ void prep_all(const float* __restrict__ c1w, const float* __restrict__ c2w,
                         const float* __restrict__ c3w, const float* __restrict__ f1w,
                         const float* __restrict__ f2w, const float* __restrict__ f3w,
                         const float* __restrict__ f4w, const float* __restrict__ f5w,
                         ushort_t* wc1, ushort_t* wc2, ushort_t* wc3,
                         ushort_t* wf1, ushort_t* wf2, ushort_t* wf3,
                         ushort_t* wf4, ushort_t* wf5) {
    __shared__ ushort_t t[32][33];
    int b = blockIdx.x;
    int tid = threadIdx.x;
    if (b < 372) {
        int idx = b * 256 + tid;
        if (idx < 3072)        prep_elem(c1w, wc1, idx, 3, 4, 8);
        else if (idx < 21504)  prep_elem(c2w, wc2, idx - 3072, 32, 32, 3);
        else if (idx < 95232)  prep_elem(c3w, wc3, idx - 21504, 64, 64, 3);
        return;
    }
    b -= 372;
    const float* W; ushort_t* WT; int K, N, ntk; bool fc1 = false; int tile;
    if (b < 2048)      { fc1 = true; tile = b;        W = f1w; WT = wf1; K = 2048; N = 1024; ntk = 64; }
    else if (b < 3072) { tile = b - 2048;             W = f2w; WT = wf2; K = 1024; N = 1024; ntk = 32; }
    else if (b < 4096) { tile = b - 3072;             W = f3w; WT = wf3; K = 1024; N = 1024; ntk = 32; }
    else if (b < 5120) { tile = b - 4096;             W = f4w; WT = wf4; K = 1024; N = 1024; ntk = 32; }
    else               { tile = b - 5120;             W = f5w; WT = wf5; K = 1024; N = 256;  ntk = 32; }
    int kb = (tile % ntk) * 32, nb = (tile / ntk) * 32;
    int tx = tid & 31, ty = tid >> 5;
    if (!fc1) {
#pragma unroll
        for (int i = 0; i < 32; i += 8)
            t[ty + i][tx] = f2bf(W[(size_t)(kb + ty + i) * N + nb + tx]);
    } else {
        int hw = kb >> 7, c0 = kb & 127;
#pragma unroll
        for (int i = 0; i < 32; i += 8)
            t[ty + i][tx] = f2bf(W[(size_t)((c0 + ty + i) * 16 + hw) * 1024 + nb + tx]);
    }
    __syncthreads();
#pragma unroll
    for (int i = 0; i < 32; i += 8)
        WT[(size_t)(nb + ty + i) * K + kb + tx] = t[tx][ty + i];
}

// ---------------------------------------------------------------------------
// FUSED shuffle + conv1(3->32) + relu + pool (r18: XCD-chunked, 39 KB LDS).
// ---------------------------------------------------------------------------
__global__ __launch_bounds__(256, 4)
void shuffle_conv1(const float* __restrict__ x, const int* __restrict__ ids,
                   const ushort_t* __restrict__ WT, const float* __restrict__ bias,
                   ushort_t* __restrict__ Y) {
    __shared__ ushort_t Xs[4 * 32 * 39 * 4];   // 39 KB
    const int tid = threadIdx.x;
    const int wid = tid >> 6, lane = tid & 63;
    const int l15 = lane & 15, l4 = lane >> 4;
    const int b = blockIdx.x;
    const int xcd = b & 7, s = b >> 3;
    const int ph = s & 15;
    const int n0 = (((s >> 4) << 3) + xcd) << 5;
    const int wn = wid & 1, wp = wid >> 1;

#pragma unroll
    for (int it = 0; it < 2; ++it) {
        int task = it * 256 + tid;
        int rr = task >> 7;
        int nl = (task >> 2) & 31;
        int q  = task & 3;
        int ih = 2 * ph - 1 + rr;
        int n  = n0 + nl;
        ushort_t* row = &Xs[(rr * 32 + nl) * 39 * 4];
        {
            const unsigned z2[2] = {0, 0};
            if (q == 0) {
                *(uint2*)&row[0] = *(const uint2*)z2;
            } else {
                int base = 31 + q * 2;
                *(uint2*)&row[base * 4]       = *(const uint2*)z2;
                *(uint2*)&row[(base + 1) * 4] = *(const uint2*)z2;
            }
        }
        f32x4 v0a = {0.f,0.f,0.f,0.f}, v0b = v0a, v1a = v0a, v1b = v0a, v2a = v0a, v2b = v0a;
        if ((unsigned)ih < 32u) {
            int j  = ((ih >> 3) << 2) | q;
            int p  = ids[(n << 4) + j];
            int sh = ((p >> 2) << 3) | (ih & 7);
            int sw = (p & 3) << 3;
            const float* src = x + (size_t)n * 3072 + (sh << 5) + sw;
            v0a = *(const f32x4*)(src);        v0b = *(const f32x4*)(src + 4);
            v1a = *(const f32x4*)(src + 1024); v1b = *(const f32x4*)(src + 1028);
            v2a = *(const f32x4*)(src + 2048); v2b = *(const f32x4*)(src + 2052);
        }
        ushort_t* dst = &row[(q * 8 + 1) * 4];
#pragma unroll
        for (int e = 0; e < 8; ++e) {
            float f0 = (e < 4) ? v0a[e & 3] : v0b[e & 3];
            float f1 = (e < 4) ? v1a[e & 3] : v1b[e & 3];
            float f2 = (e < 4) ? v2a[e & 3] : v2b[e & 3];
            ushort_t u[4] = {f2bf(f0), f2bf(f1), f2bf(f2), 0};
            *(uint2*)&dst[e * 4] = *(const uint2*)u;
        }
    }

    short8 af[3][2];
#pragma unroll
    for (int kh = 0; kh < 3; ++kh)
#pragma unroll
        for (int i = 0; i < 2; ++i)
            af[kh][i] = *(const short8*)(WT + (i * 16 + l15) * 96 + kh * 32 + l4 * 8);

    __syncthreads();

    const int nlb = wn * 16 + l15;
    const int n = n0 + nlb;

#pragma unroll
    for (int pwl = 0; pwl < 8; ++pwl) {
        int pw = wp * 8 + pwl;
        f32x4 accp[2][4];
#pragma unroll
        for (int i = 0; i < 2; ++i)
#pragma unroll
            for (int p = 0; p < 4; ++p)
#pragma unroll
                for (int r = 0; r < 4; ++r) accp[i][p][r] = 0.f;

#pragma unroll
        for (int pc = 0; pc < 2; ++pc)
#pragma unroll
            for (int rr = 0; rr < 4; ++rr) {
                int w2 = 2 * pw + pc + 2 * l4;
                const ushort_t* pB = &Xs[((rr * 32 + nlb) * 39 + w2) * 4];
                short8 bf;
                *(uint2*)&bf       = *(const uint2*)pB;
                *(((uint2*)&bf)+1) = *(const uint2*)(pB + 4);
#pragma unroll
                for (int pr = 0; pr < 2; ++pr) {
                    int kh = rr - pr;
                    if (kh < 0 || kh > 2) continue;
#pragma unroll
                    for (int i = 0; i < 2; ++i)
                        accp[i][pr * 2 + pc] = __builtin_amdgcn_mfma_f32_16x16x32_bf16(
                            af[kh][i], bf, accp[i][pr * 2 + pc], 0, 0, 0);
                }
            }

#pragma unroll
        for (int i = 0; i < 2; ++i) {
            int ocb = i * 16 + l4 * 4;
            ushort_t u[4];
#pragma unroll
            for (int r = 0; r < 4; ++r) {
                float mx = fmaxf(fmaxf(accp[i][0][r], accp[i][1][r]),
                                 fmaxf(accp[i][2][r], accp[i][3][r]));
                u[r] = f2bf(fmaxf(mx + bias[ocb + r], 0.f));
            }
            *(uint2*)(Y + ((size_t)(ph * 16 + pw) * 4096 + n) * 32 + ocb) = *(const uint2*)u;
        }
    }
}

// ---------------------------------------------------------------------------
// conv2 v5: weights-in-registers row-phase GEMM (r14), MINB 2->3.
// LDS 32 KB (<=5/CU); regs ~140 -> 3 blocks/CU feasible; grid 4096 (16/CU).
// ---------------------------------------------------------------------------
__global__ __launch_bounds__(256, 3)
void conv2_gemm(const ushort_t* __restrict__ X, const ushort_t* __restrict__ WT,
                const float* __restrict__ bias, ushort_t* __restrict__ Y) {
    __shared__ ushort_t Bs[2][4 * 64 * 32];
    const int tid = threadIdx.x;
    const int wid = tid >> 6, lane = tid & 63;
    const int l15 = lane & 15, l4 = lane >> 4;
    const int orig = blockIdx.x;
    const int lin = (orig & 7) * 512 + (orig >> 3);
    const int pos = lin & 63;
    const int n0 = (lin >> 6) * 64;
    const int ph = pos >> 3, pw = pos & 7;

    short8 af[9];
#pragma unroll
    for (int t = 0; t < 9; ++t)
        af[t] = *(const short8*)(WT + (size_t)(wid * 16 + l15) * 288 + (t * 4 + l4) * 8);

    f32x4 acc[4][4];
#pragma unroll
    for (int p = 0; p < 4; ++p)
#pragma unroll
        for (int j = 0; j < 4; ++j)
#pragma unroll
            for (int r = 0; r < 4; ++r) acc[p][j][r] = 0.f;

    {
        int ih = 2 * ph - 1;
        if (ih >= 0) {
#pragma unroll
            for (int dw = 0; dw < 4; ++dw) {
                int iw = 2 * pw - 1 + dw;
                if ((unsigned)iw >= 16u) continue;
                int m = tid >> 2, ss = tid & 3;
                int cc = ss ^ ((m >> 1) & 3);
                gload_lds16(X + ((size_t)(ih * 16 + iw) * 4096 + n0 + m) * 32 + cc * 8,
                            &Bs[0][dw * 2048 + wid * 512]);
            }
        }
    }
    __syncthreads();

#pragma unroll
    for (int r = 0; r < 4; ++r) {
        const int cur = r & 1;
        if (r < 3) {
            int ihn = 2 * ph + r;
            if (ihn < 16) {
#pragma unroll
                for (int dw = 0; dw < 4; ++dw) {
                    int iw = 2 * pw - 1 + dw;
                    if ((unsigned)iw >= 16u) continue;
                    int m = tid >> 2, ss = tid & 3;
                    int cc = ss ^ ((m >> 1) & 3);
                    gload_lds16(X + ((size_t)(ihn * 16 + iw) * 4096 + n0 + m) * 32 + cc * 8,
                                &Bs[cur ^ 1][dw * 2048 + wid * 512]);
                }
            }
        }
        int ih = 2 * ph - 1 + r;
        if ((unsigned)ih < 16u) {
#pragma unroll
            for (int dw = 0; dw < 4; ++dw) {
                int iw = 2 * pw - 1 + dw;
                if ((unsigned)iw >= 16u) continue;
                short8 bf[4];
#pragma unroll
                for (int j = 0; j < 4; ++j) {
                    int m2 = j * 16 + l15;
                    bf[j] = *(const short8*)(
                        &Bs[cur][(dw * 64 + m2) * 32 + ((l4 ^ ((m2 >> 1) & 3)) * 8)]);
                }
#pragma unroll
                for (int pr = 0; pr < 2; ++pr) {
                    int kh = r - pr;
                    if (kh < 0 || kh > 2) continue;
#pragma unroll
                    for (int pc = 0; pc < 2; ++pc) {
                        int kw = dw - pc;
                        if (kw < 0 || kw > 2) continue;
                        int tap = kh * 3 + kw;
#pragma unroll
                        for (int j = 0; j < 4; ++j)
                            acc[pr * 2 + pc][j] =
                                __builtin_amdgcn_mfma_f32_16x16x32_bf16(
                                    af[tap], bf[j], acc[pr * 2 + pc][j], 0, 0, 0);
                    }
                }
            }
        }
        __syncthreads();
    }

    {
        int oc_l = wid * 16 + l4 * 4;
#pragma unroll
        for (int j = 0; j < 4; ++j) {
            int n = n0 + j * 16 + l15;
            ushort_t u[4];
#pragma unroll
            for (int r = 0; r < 4; ++r) {
                float mx = fmaxf(fmaxf(acc[0][j][r], acc[1][j][r]),
                                 fmaxf(acc[2][j][r], acc[3][j][r]));
                u[r] = f2bf(fmaxf(mx + bias[oc_l + r], 0.f));
            }
            *(uint2*)(Y + ((size_t)pos * 4096 + n) * 64 + oc_l) = *(const uint2*)u;
        }
    }
}

// ---------------------------------------------------------------------------
// conv3: EXACT r18 structure (pos x 128n x 128oc, 32 KB LDS, 2-barrier steps).
// ---------------------------------------------------------------------------
template <int IC, int H, int OC, bool FC_EPI, int MINB>
__global__ __launch_bounds__(256, MINB)
void conv_gemm(const ushort_t* __restrict__ X, const ushort_t* __restrict__ WT,
               const float* __restrict__ bias, ushort_t* __restrict__ Y) {
    constexpr int PW = H / 2;
    constexpr int K  = 9 * IC;
    constexpr int CH = IC / 8;
    constexpr int CM = CH - 1;
    constexpr int KK = IC / 32;
    constexpr int WM = (OC == 128) ? 2 : 1;
    constexpr int WN = 4 / WM;
    constexpr int WTM = OC / WM / 16;
    constexpr int WTN = 128 / WN / 16;
    constexpr int APASS = OC * CH / 256;
    constexpr int BPASS = 128 * CH / 256;
    constexpr int NPOS = PW * PW;

    __shared__ ushort_t As[OC * IC];
    __shared__ ushort_t Bs[128 * IC];
    const int tid = threadIdx.x;
    const int wid = tid >> 6, lane = tid & 63;
    const int wm = wid / WN, wn = wid % WN;
    const int l15 = lane & 15, l4 = lane >> 4;
    const int orig = blockIdx.x;
    const int nwg = NPOS * 32;
    const int lin = (orig & 7) * (nwg / 8) + (orig >> 3);
    const int ph = (lin % NPOS) / PW, pw = (lin % NPOS) % PW;
    const int n0 = (lin / NPOS) * 128;

    f32x4 acc[WTM][WTN], mx[WTM][WTN];

    for (int p = 0; p < 4; ++p) {
#pragma unroll
        for (int i = 0; i < WTM; ++i)
#pragma unroll
            for (int j = 0; j < WTN; ++j)
#pragma unroll
                for (int r = 0; r < 4; ++r) acc[i][j][r] = 0.f;
        const int pr = p >> 1, pc = p & 1;
        for (int t = 0; t < 9; ++t) {
            const int kh = t / 3, kw = t % 3;
            const int ih = 2 * ph + pr - 1 + kh;
            const int iw = 2 * pw + pc - 1 + kw;
            if ((unsigned)ih >= (unsigned)H || (unsigned)iw >= (unsigned)H) continue;
            __syncthreads();
            const ushort_t* bsrc = X + (size_t)(ih * H + iw) * 4096 * IC + (size_t)n0 * IC;
#pragma unroll
            for (int pass = 0; pass < APASS; ++pass) {
                int idx = pass * 256 + tid;
                int m = idx / CH, ss = idx % CH;
                int cc = ss ^ (m & CM);
                gload_lds16(WT + (size_t)m * K + t * IC + cc * 8,
                            &As[(pass * 256 + wid * 64) * 8]);
            }
#pragma unroll
            for (int pass = 0; pass < BPASS; ++pass) {
                int idx = pass * 256 + tid;
                int m = idx / CH, ss = idx % CH;
                int cc = ss ^ (m & CM);
                gload_lds16(bsrc + (size_t)m * IC + cc * 8,
                            &Bs[(pass * 256 + wid * 64) * 8]);
            }
            __syncthreads();
#pragma unroll
            for (int kk = 0; kk < KK; ++kk) {
                short8 af[WTM], bf[WTN];
                int c = kk * 4 + l4;
#pragma unroll
                for (int i = 0; i < WTM; ++i) {
                    int m = wm * (WTM * 16) + i * 16 + l15;
                    af[i] = *(const short8*)(As + m * IC + ((c ^ (m & CM)) * 8));
                }
#pragma unroll
                for (int j = 0; j < WTN; ++j) {
                    int m = wn * (WTN * 16) + j * 16 + l15;
                    bf[j] = *(const short8*)(Bs + m * IC + ((c ^ (m & CM)) * 8));
                }
#pragma unroll
                for (int i = 0; i < WTM; ++i)
#pragma unroll
                    for (int j = 0; j < WTN; ++j)
                        acc[i][j] = __builtin_amdgcn_mfma_f32_16x16x32_bf16(
                            af[i], bf[j], acc[i][j], 0, 0, 0);
            }
        }
#pragma unroll
        for (int i = 0; i < WTM; ++i)
#pragma unroll
            for (int j = 0; j < WTN; ++j)
#pragma unroll
                for (int r = 0; r < 4; ++r)
                    mx[i][j][r] = (p == 0) ? acc[i][j][r]
                                           : fmaxf(mx[i][j][r], acc[i][j][r]);
    }

#pragma unroll
    for (int i = 0; i < WTM; ++i) {
        int oc_l = wm * (WTM * 16) + i * 16 + l4 * 4;
#pragma unroll
        for (int j = 0; j < WTN; ++j) {
            int n = n0 + wn * (WTN * 16) + j * 16 + l15;
            ushort_t u[4];
#pragma unroll
            for (int r = 0; r < 4; ++r)
                u[r] = f2bf(fmaxf(mx[i][j][r] + bias[oc_l + r], 0.f));
            if (FC_EPI)
                *(uint2*)(Y + (size_t)n * 2048 + (ph * 4 + pw) * 128 + oc_l) = *(const uint2*)u;
            else
                *(uint2*)(Y + ((size_t)(ph * PW + pw) * 4096 + n) * OC + oc_l) = *(const uint2*)u;
        }
    }
}

// ---------------------------------------------------------------------------
// FC GEMM v3: 64M x 64N tile, BK=64, dbuf -> 32 KB LDS -> 4 blocks/CU (r24).
// ---------------------------------------------------------------------------
template <bool RELU, bool F32OUT>
__global__ __launch_bounds__(256, 4)
void fc_mfma(const ushort_t* __restrict__ A, const ushort_t* __restrict__ BT,
             const float* __restrict__ bias, void* __restrict__ Cout,
             int M, int N, int K) {
    __shared__ ushort_t As[2][64 * 64];
    __shared__ ushort_t Bs[2][64 * 64];
    const int tid = threadIdx.x;
    const int wid = tid >> 6, lane = tid & 63;
    const int wr = wid >> 1, wc = wid & 1;
    const int tm = blockIdx.y * 64, tn = blockIdx.x * 64;
    const int l15 = lane & 15, l4 = lane >> 4;

    f32x4 acc[2][2];
#pragma unroll
    for (int i = 0; i < 2; ++i)
#pragma unroll
        for (int j = 0; j < 2; ++j)
#pragma unroll
            for (int r = 0; r < 4; ++r) acc[i][j][r] = 0.f;

    const int NT = K >> 6;
#pragma unroll
    for (int pass = 0; pass < 2; ++pass) {
        int m = pass * 32 + (tid >> 3);
        int cc = (tid & 7) ^ (m & 7);
        gload_lds16(A + (size_t)(tm + m) * K + cc * 8,
                    &As[0][(pass * 256 + wid * 64) * 8]);
        gload_lds16(BT + (size_t)(tn + m) * K + cc * 8,
                    &Bs[0][(pass * 256 + wid * 64) * 8]);
    }
    __syncthreads();

    for (int t = 0; t < NT; ++t) {
        const int cur = t & 1, nxt = cur ^ 1;
        if (t + 1 < NT) {
            const int k1 = (t + 1) << 6;
#pragma unroll
            for (int pass = 0; pass < 2; ++pass) {
                int m = pass * 32 + (tid >> 3);
                int cc = (tid & 7) ^ (m & 7);
                gload_lds16(A + (size_t)(tm + m) * K + k1 + cc * 8,
                            &As[nxt][(pass * 256 + wid * 64) * 8]);
                gload_lds16(BT + (size_t)(tn + m) * K + k1 + cc * 8,
                            &Bs[nxt][(pass * 256 + wid * 64) * 8]);
            }
        }
#pragma unroll
        for (int kk = 0; kk < 2; ++kk) {
            short8 af[2], bfr[2];
            int c = kk * 4 + l4;
#pragma unroll
            for (int i = 0; i < 2; ++i) {
                int m = wr * 32 + i * 16 + l15;
                af[i] = *(const short8*)(&As[cur][m * 64 + (c ^ (m & 7)) * 8]);
                int nn = wc * 32 + i * 16 + l15;
                bfr[i] = *(const short8*)(&Bs[cur][nn * 64 + (c ^ (nn & 7)) * 8]);
            }
#pragma unroll
            for (int i = 0; i < 2; ++i)
#pragma unroll
                for (int j = 0; j < 2; ++j)
                    acc[i][j] = __builtin_amdgcn_mfma_f32_16x16x32_bf16(
                        af[i], bfr[j], acc[i][j], 0, 0, 0);
        }
        __syncthreads();
    }

#pragma unroll
    for (int i = 0; i < 2; ++i) {
        int row = tm + wr * 32 + i * 16 + l4 * 4;
#pragma unroll
        for (int j = 0; j < 2; ++j) {
            int col = tn + wc * 32 + j * 16 + l15;
            float bv = bias[col];
#pragma unroll
            for (int r = 0; r < 4; ++r) {
                float v = acc[i][j][r] + bv;
                if (RELU) v = fmaxf(v, 0.f);
                if (F32OUT)
                    ((float*)Cout)[(size_t)(row + r) * N + col] = v;
                else
                    ((ushort_t*)Cout)[(size_t)(row + r) * N + col] = f2bf(v);
            }
        }
    }
}

// ---------------------------------------------------------------------------
extern "C" void kernel_launch(void* const* d_in, const int* in_sizes, int n_in,
                              void* d_out, int out_size, void* d_ws, size_t ws_size,
                              hipStream_t stream) {
    const float* x     = (const float*)d_in[0];
    const float* noise = (const float*)d_in[1];
    const float* c1w = (const float*)d_in[2];  const float* c1b = (const float*)d_in[3];
    const float* c2w = (const float*)d_in[4];  const float* c2b = (const float*)d_in[5];
    const float* c3w = (const float*)d_in[6];  const float* c3b = (const float*)d_in[7];
    const float* f1w = (const float*)d_in[8];  const float* f1b = (const float*)d_in[9];
    const float* f2w = (const float*)d_in[10]; const float* f2b = (const float*)d_in[11];
    const float* f3w = (const float*)d_in[12]; const float* f3b = (const float*)d_in[13];
    const float* f4w = (const float*)d_in[14]; const float* f4b = (const float*)d_in[15];
    const float* f5w = (const float*)d_in[16]; const float* f5b = (const float*)d_in[17];
    float* out = (float*)d_out;

    char* ws = (char*)d_ws;
    const size_t MB = 1ull << 20;
    int*      ids  = (int*)ws;                               // 256 KB
    ushort_t* wc1  = (ushort_t*)(ws + 1 * MB);               // 6 KB
    ushort_t* wc2  = (ushort_t*)(ws + 1 * MB + 64 * 1024);   // 36 KB
    ushort_t* wc3  = (ushort_t*)(ws + 1 * MB + 128 * 1024);  // 144 KB
    ushort_t* wf1  = (ushort_t*)(ws + 2 * MB);               // 4 MB
    ushort_t* wf2  = (ushort_t*)(ws + 6 * MB);               // 2 MB
    ushort_t* wf3  = (ushort_t*)(ws + 8 * MB);               // 2 MB
    ushort_t* wf4  = (ushort_t*)(ws + 10 * MB);              // 2 MB
    ushort_t* wf5  = (ushort_t*)(ws + 12 * MB);              // 0.5 MB
    ushort_t* act1 = (ushort_t*)(ws + 89 * MB);              // 64 MB  [256pos][4096n][32oc]
    ushort_t* act2 = (ushort_t*)(ws + 153 * MB);             // 32 MB  [64pos][4096n][64oc]
    ushort_t* act3 = (ushort_t*)(ws + 185 * MB);             // 16 MB  [4096][2048]
    ushort_t* fcb1 = (ushort_t*)(ws + 201 * MB);             // 8 MB
    ushort_t* fcb2 = (ushort_t*)(ws + 209 * MB);             // 8 MB

    // all weight preps in one launch
    prep_all<<<dim3(5748), 256, 0, stream>>>(c1w, c2w, c3w, f1w, f2w, f3w, f4w, f5w,
                                             wc1, wc2, wc3, wf1, wf2, wf3, wf4, wf5);

    // rank + fused shuffle/conv1 (XCD-chunked grid)
    rank_kernel<<<BATCH / 256, 256, 0, stream>>>(noise, ids, out + (size_t)BATCH * 256);
    shuffle_conv1<<<dim3(2048), 256, 0, stream>>>(x, ids, wc1, c1b, act1);

    // conv2 (MINB 3) / conv3
    conv2_gemm<<<dim3(4096), 256, 0, stream>>>(act1, wc2, c2b, act2);
    conv_gemm<64, 8, 128, true, 2><<<dim3(512), 256, 0, stream>>>(act2, wc3, c3b, act3);

    // FC chain (64x64 tiles, 4 blocks/CU)
    fc_mfma<true,  false><<<dim3(16, 64), 256, 0, stream>>>(act3, wf1, f1b, fcb1, BATCH, 1024, 2048);
    fc_mfma<true,  false><<<dim3(16, 64), 256, 0, stream>>>(fcb1, wf2, f2b, fcb2, BATCH, 1024, 1024);
    fc_mfma<true,  false><<<dim3(16, 64), 256, 0, stream>>>(fcb2, wf3, f3b, fcb1, BATCH, 1024, 1024);
    fc_mfma<true,  false><<<dim3(16, 64), 256, 0, stream>>>(fcb1, wf4, f4b, fcb2, BATCH, 1024, 1024);
    fc_mfma<false, true ><<<dim3(4, 64),  256, 0, stream>>>(fcb2, wf5, f5b, out, BATCH, 256, 1024);
}

// Round 26
// 226.245 us; speedup vs baseline: 1.0174x; 1.0174x over previous
//
#include <hip/hip_runtime.h>

#define BATCH 4096
#define NPATCH 16

typedef __attribute__((ext_vector_type(8)))  short  short8;
typedef __attribute__((ext_vector_type(4)))  float  f32x4;
typedef unsigned short ushort_t;

__device__ __forceinline__ ushort_t f2bf(float f) {
    union { float f; unsigned u; } x; x.f = f;
    unsigned r = x.u + 0x7FFFu + ((x.u >> 16) & 1u);
    return (ushort_t)(r >> 16);
}

__device__ __forceinline__ void gload_lds16(const void* g, void* l) {
    __builtin_amdgcn_global_load_lds((const __attribute__((address_space(1))) void*)g,
                                     (__attribute__((address_space(3))) void*)l, 16, 0, 0);
}

// ---------------------------------------------------------------------------
// rank: ids_shuffle (ws) + ids_restore -> target (f32, d_out tail)
// ---------------------------------------------------------------------------
__global__ void rank_kernel(const float* __restrict__ noise,
                            int* __restrict__ ids_shuffle,
                            float* __restrict__ target_out) {
    int n = blockIdx.x * 256 + threadIdx.x;
    if (n >= BATCH) return;
    float v[NPATCH];
#pragma unroll
    for (int i = 0; i < NPATCH; i++) v[i] = noise[n * NPATCH + i];
#pragma unroll
    for (int j = 0; j < NPATCH; j++) {
        int r = 0;
#pragma unroll
        for (int i = 0; i < NPATCH; i++)
            if (v[i] < v[j] || (v[i] == v[j] && i < j)) r++;
        ids_shuffle[n * NPATCH + r] = j;
        target_out[n * NPATCH + j] = (float)r;
    }
}

// ---------------------------------------------------------------------------
// prep_all: ALL weight preps in ONE launch (r18).
// ---------------------------------------------------------------------------
__device__ __forceinline__ void prep_elem(const float* W, ushort_t* WT, int idx,
                                          int IC, int ICP, int KWP) {
    int KP = 3 * KWP * ICP;
    int oc = idx / KP, k = idx % KP;
    int kh = k / (KWP * ICP);
    int kw = (k / ICP) % KWP;
    int ic = k % ICP;
    ushort_t v = 0;
    if (kw < 3 && ic < IC)
        v = f2bf(W[((oc * IC + ic) * 3 + kh) * 3 + kw]);
    WT[idx] = v;
}

__global__ void prep_all(const float* __restrict__ c1w, const float* __restrict__ c2w,
                         const float* __restrict__ c3w, const float* __restrict__ f1w,
                         const float* __restrict__ f2w, const float* __restrict__ f3w,
                         const float* __restrict__ f4w, const float* __restrict__ f5w,
                         ushort_t* wc1, ushort_t* wc2, ushort_t* wc3,
                         ushort_t* wf1, ushort_t* wf2, ushort_t* wf3,
                         ushort_t* wf4, ushort_t* wf5) {
    __shared__ ushort_t t[32][33];
    int b = blockIdx.x;
    int tid = threadIdx.x;
    if (b < 372) {
        int idx = b * 256 + tid;
        if (idx < 3072)        prep_elem(c1w, wc1, idx, 3, 4, 8);
        else if (idx < 21504)  prep_elem(c2w, wc2, idx - 3072, 32, 32, 3);
        else if (idx < 95232)  prep_elem(c3w, wc3, idx - 21504, 64, 64, 3);
        return;
    }
    b -= 372;
    const float* W; ushort_t* WT; int K, N, ntk; bool fc1 = false; int tile;
    if (b < 2048)      { fc1 = true; tile = b;        W = f1w; WT = wf1; K = 2048; N = 1024; ntk = 64; }
    else if (b < 3072) { tile = b - 2048;             W = f2w; WT = wf2; K = 1024; N = 1024; ntk = 32; }
    else if (b < 4096) { tile = b - 3072;             W = f3w; WT = wf3; K = 1024; N = 1024; ntk = 32; }
    else if (b < 5120) { tile = b - 4096;             W = f4w; WT = wf4; K = 1024; N = 1024; ntk = 32; }
    else               { tile = b - 5120;             W = f5w; WT = wf5; K = 1024; N = 256;  ntk = 32; }
    int kb = (tile % ntk) * 32, nb = (tile / ntk) * 32;
    int tx = tid & 31, ty = tid >> 5;
    if (!fc1) {
#pragma unroll
        for (int i = 0; i < 32; i += 8)
            t[ty + i][tx] = f2bf(W[(size_t)(kb + ty + i) * N + nb + tx]);
    } else {
        int hw = kb >> 7, c0 = kb & 127;
#pragma unroll
        for (int i = 0; i < 32; i += 8)
            t[ty + i][tx] = f2bf(W[(size_t)((c0 + ty + i) * 16 + hw) * 1024 + nb + tx]);
    }
    __syncthreads();
#pragma unroll
    for (int i = 0; i < 32; i += 8)
        WT[(size_t)(nb + ty + i) * K + kb + tx] = t[tx][ty + i];
}

// ---------------------------------------------------------------------------
// FUSED shuffle + conv1(3->32) + relu + pool (r18: XCD-chunked, 39 KB LDS).
// ---------------------------------------------------------------------------
__global__ __launch_bounds__(256, 4)
void shuffle_conv1(const float* __restrict__ x, const int* __restrict__ ids,
                   const ushort_t* __restrict__ WT, const float* __restrict__ bias,
                   ushort_t* __restrict__ Y) {
    __shared__ ushort_t Xs[4 * 32 * 39 * 4];   // 39 KB
    const int tid = threadIdx.x;
    const int wid = tid >> 6, lane = tid & 63;
    const int l15 = lane & 15, l4 = lane >> 4;
    const int b = blockIdx.x;
    const int xcd = b & 7, s = b >> 3;
    const int ph = s & 15;
    const int n0 = (((s >> 4) << 3) + xcd) << 5;
    const int wn = wid & 1, wp = wid >> 1;

#pragma unroll
    for (int it = 0; it < 2; ++it) {
        int task = it * 256 + tid;
        int rr = task >> 7;
        int nl = (task >> 2) & 31;
        int q  = task & 3;
        int ih = 2 * ph - 1 + rr;
        int n  = n0 + nl;
        ushort_t* row = &Xs[(rr * 32 + nl) * 39 * 4];
        {
            const unsigned z2[2] = {0, 0};
            if (q == 0) {
                *(uint2*)&row[0] = *(const uint2*)z2;
            } else {
                int base = 31 + q * 2;
                *(uint2*)&row[base * 4]       = *(const uint2*)z2;
                *(uint2*)&row[(base + 1) * 4] = *(const uint2*)z2;
            }
        }
        f32x4 v0a = {0.f,0.f,0.f,0.f}, v0b = v0a, v1a = v0a, v1b = v0a, v2a = v0a, v2b = v0a;
        if ((unsigned)ih < 32u) {
            int j  = ((ih >> 3) << 2) | q;
            int p  = ids[(n << 4) + j];
            int sh = ((p >> 2) << 3) | (ih & 7);
            int sw = (p & 3) << 3;
            const float* src = x + (size_t)n * 3072 + (sh << 5) + sw;
            v0a = *(const f32x4*)(src);        v0b = *(const f32x4*)(src + 4);
            v1a = *(const f32x4*)(src + 1024); v1b = *(const f32x4*)(src + 1028);
            v2a = *(const f32x4*)(src + 2048); v2b = *(const f32x4*)(src + 2052);
        }
        ushort_t* dst = &row[(q * 8 + 1) * 4];
#pragma unroll
        for (int e = 0; e < 8; ++e) {
            float f0 = (e < 4) ? v0a[e & 3] : v0b[e & 3];
            float f1 = (e < 4) ? v1a[e & 3] : v1b[e & 3];
            float f2 = (e < 4) ? v2a[e & 3] : v2b[e & 3];
            ushort_t u[4] = {f2bf(f0), f2bf(f1), f2bf(f2), 0};
            *(uint2*)&dst[e * 4] = *(const uint2*)u;
        }
    }

    short8 af[3][2];
#pragma unroll
    for (int kh = 0; kh < 3; ++kh)
#pragma unroll
        for (int i = 0; i < 2; ++i)
            af[kh][i] = *(const short8*)(WT + (i * 16 + l15) * 96 + kh * 32 + l4 * 8);

    __syncthreads();

    const int nlb = wn * 16 + l15;
    const int n = n0 + nlb;

#pragma unroll
    for (int pwl = 0; pwl < 8; ++pwl) {
        int pw = wp * 8 + pwl;
        f32x4 accp[2][4];
#pragma unroll
        for (int i = 0; i < 2; ++i)
#pragma unroll
            for (int p = 0; p < 4; ++p)
#pragma unroll
                for (int r = 0; r < 4; ++r) accp[i][p][r] = 0.f;

#pragma unroll
        for (int pc = 0; pc < 2; ++pc)
#pragma unroll
            for (int rr = 0; rr < 4; ++rr) {
                int w2 = 2 * pw + pc + 2 * l4;
                const ushort_t* pB = &Xs[((rr * 32 + nlb) * 39 + w2) * 4];
                short8 bf;
                *(uint2*)&bf       = *(const uint2*)pB;
                *(((uint2*)&bf)+1) = *(const uint2*)(pB + 4);
#pragma unroll
                for (int pr = 0; pr < 2; ++pr) {
                    int kh = rr - pr;
                    if (kh < 0 || kh > 2) continue;
#pragma unroll
                    for (int i = 0; i < 2; ++i)
                        accp[i][pr * 2 + pc] = __builtin_amdgcn_mfma_f32_16x16x32_bf16(
                            af[kh][i], bf, accp[i][pr * 2 + pc], 0, 0, 0);
                }
            }

#pragma unroll
        for (int i = 0; i < 2; ++i) {
            int ocb = i * 16 + l4 * 4;
            ushort_t u[4];
#pragma unroll
            for (int r = 0; r < 4; ++r) {
                float mx = fmaxf(fmaxf(accp[i][0][r], accp[i][1][r]),
                                 fmaxf(accp[i][2][r], accp[i][3][r]));
                u[r] = f2bf(fmaxf(mx + bias[ocb + r], 0.f));
            }
            *(uint2*)(Y + ((size_t)(ph * 16 + pw) * 4096 + n) * 32 + ocb) = *(const uint2*)u;
        }
    }
}

// ---------------------------------------------------------------------------
// conv2 v5: weights-in-registers row-phase GEMM (r14, MINB 2 — measured best).
// ---------------------------------------------------------------------------
__global__ __launch_bounds__(256, 2)
void conv2_gemm(const ushort_t* __restrict__ X, const ushort_t* __restrict__ WT,
                const float* __restrict__ bias, ushort_t* __restrict__ Y) {
    __shared__ ushort_t Bs[2][4 * 64 * 32];
    const int tid = threadIdx.x;
    const int wid = tid >> 6, lane = tid & 63;
    const int l15 = lane & 15, l4 = lane >> 4;
    const int orig = blockIdx.x;
    const int lin = (orig & 7) * 512 + (orig >> 3);
    const int pos = lin & 63;
    const int n0 = (lin >> 6) * 64;
    const int ph = pos >> 3, pw = pos & 7;

    short8 af[9];
#pragma unroll
    for (int t = 0; t < 9; ++t)
        af[t] = *(const short8*)(WT + (size_t)(wid * 16 + l15) * 288 + (t * 4 + l4) * 8);

    f32x4 acc[4][4];
#pragma unroll
    for (int p = 0; p < 4; ++p)
#pragma unroll
        for (int j = 0; j < 4; ++j)
#pragma unroll
            for (int r = 0; r < 4; ++r) acc[p][j][r] = 0.f;

    {
        int ih = 2 * ph - 1;
        if (ih >= 0) {
#pragma unroll
            for (int dw = 0; dw < 4; ++dw) {
                int iw = 2 * pw - 1 + dw;
                if ((unsigned)iw >= 16u) continue;
                int m = tid >> 2, ss = tid & 3;
                int cc = ss ^ ((m >> 1) & 3);
                gload_lds16(X + ((size_t)(ih * 16 + iw) * 4096 + n0 + m) * 32 + cc * 8,
                            &Bs[0][dw * 2048 + wid * 512]);
            }
        }
    }
    __syncthreads();

#pragma unroll
    for (int r = 0; r < 4; ++r) {
        const int cur = r & 1;
        if (r < 3) {
            int ihn = 2 * ph + r;
            if (ihn < 16) {
#pragma unroll
                for (int dw = 0; dw < 4; ++dw) {
                    int iw = 2 * pw - 1 + dw;
                    if ((unsigned)iw >= 16u) continue;
                    int m = tid >> 2, ss = tid & 3;
                    int cc = ss ^ ((m >> 1) & 3);
                    gload_lds16(X + ((size_t)(ihn * 16 + iw) * 4096 + n0 + m) * 32 + cc * 8,
                                &Bs[cur ^ 1][dw * 2048 + wid * 512]);
                }
            }
        }
        int ih = 2 * ph - 1 + r;
        if ((unsigned)ih < 16u) {
#pragma unroll
            for (int dw = 0; dw < 4; ++dw) {
                int iw = 2 * pw - 1 + dw;
                if ((unsigned)iw >= 16u) continue;
                short8 bf[4];
#pragma unroll
                for (int j = 0; j < 4; ++j) {
                    int m2 = j * 16 + l15;
                    bf[j] = *(const short8*)(
                        &Bs[cur][(dw * 64 + m2) * 32 + ((l4 ^ ((m2 >> 1) & 3)) * 8)]);
                }
#pragma unroll
                for (int pr = 0; pr < 2; ++pr) {
                    int kh = r - pr;
                    if (kh < 0 || kh > 2) continue;
#pragma unroll
                    for (int pc = 0; pc < 2; ++pc) {
                        int kw = dw - pc;
                        if (kw < 0 || kw > 2) continue;
                        int tap = kh * 3 + kw;
#pragma unroll
                        for (int j = 0; j < 4; ++j)
                            acc[pr * 2 + pc][j] =
                                __builtin_amdgcn_mfma_f32_16x16x32_bf16(
                                    af[tap], bf[j], acc[pr * 2 + pc][j], 0, 0, 0);
                    }
                }
            }
        }
        __syncthreads();
    }

    {
        int oc_l = wid * 16 + l4 * 4;
#pragma unroll
        for (int j = 0; j < 4; ++j) {
            int n = n0 + j * 16 + l15;
            ushort_t u[4];
#pragma unroll
            for (int r = 0; r < 4; ++r) {
                float mx = fmaxf(fmaxf(acc[0][j][r], acc[1][j][r]),
                                 fmaxf(acc[2][j][r], acc[3][j][r]));
                u[r] = f2bf(fmaxf(mx + bias[oc_l + r], 0.f));
            }
            *(uint2*)(Y + ((size_t)pos * 4096 + n) * 64 + oc_l) = *(const uint2*)u;
        }
    }
}

// ---------------------------------------------------------------------------
// conv3: EXACT r18 structure (pos x 128n x 128oc, 32 KB LDS, 2-barrier steps).
// ---------------------------------------------------------------------------
template <int IC, int H, int OC, bool FC_EPI, int MINB>
__global__ __launch_bounds__(256, MINB)
void conv_gemm(const ushort_t* __restrict__ X, const ushort_t* __restrict__ WT,
               const float* __restrict__ bias, ushort_t* __restrict__ Y) {
    constexpr int PW = H / 2;
    constexpr int K  = 9 * IC;
    constexpr int CH = IC / 8;
    constexpr int CM = CH - 1;
    constexpr int KK = IC / 32;
    constexpr int WM = (OC == 128) ? 2 : 1;
    constexpr int WN = 4 / WM;
    constexpr int WTM = OC / WM / 16;
    constexpr int WTN = 128 / WN / 16;
    constexpr int APASS = OC * CH / 256;
    constexpr int BPASS = 128 * CH / 256;
    constexpr int NPOS = PW * PW;

    __shared__ ushort_t As[OC * IC];
    __shared__ ushort_t Bs[128 * IC];
    const int tid = threadIdx.x;
    const int wid = tid >> 6, lane = tid & 63;
    const int wm = wid / WN, wn = wid % WN;
    const int l15 = lane & 15, l4 = lane >> 4;
    const int orig = blockIdx.x;
    const int nwg = NPOS * 32;
    const int lin = (orig & 7) * (nwg / 8) + (orig >> 3);
    const int ph = (lin % NPOS) / PW, pw = (lin % NPOS) % PW;
    const int n0 = (lin / NPOS) * 128;

    f32x4 acc[WTM][WTN], mx[WTM][WTN];

    for (int p = 0; p < 4; ++p) {
#pragma unroll
        for (int i = 0; i < WTM; ++i)
#pragma unroll
            for (int j = 0; j < WTN; ++j)
#pragma unroll
                for (int r = 0; r < 4; ++r) acc[i][j][r] = 0.f;
        const int pr = p >> 1, pc = p & 1;
        for (int t = 0; t < 9; ++t) {
            const int kh = t / 3, kw = t % 3;
            const int ih = 2 * ph + pr - 1 + kh;
            const int iw = 2 * pw + pc - 1 + kw;
            if ((unsigned)ih >= (unsigned)H || (unsigned)iw >= (unsigned)H) continue;
            __syncthreads();
            const ushort_t* bsrc = X + (size_t)(ih * H + iw) * 4096 * IC + (size_t)n0 * IC;
#pragma unroll
            for (int pass = 0; pass < APASS; ++pass) {
                int idx = pass * 256 + tid;
                int m = idx / CH, ss = idx % CH;
                int cc = ss ^ (m & CM);
                gload_lds16(WT + (size_t)m * K + t * IC + cc * 8,
                            &As[(pass * 256 + wid * 64) * 8]);
            }
#pragma unroll
            for (int pass = 0; pass < BPASS; ++pass) {
                int idx = pass * 256 + tid;
                int m = idx / CH, ss = idx % CH;
                int cc = ss ^ (m & CM);
                gload_lds16(bsrc + (size_t)m * IC + cc * 8,
                            &Bs[(pass * 256 + wid * 64) * 8]);
            }
            __syncthreads();
#pragma unroll
            for (int kk = 0; kk < KK; ++kk) {
                short8 af[WTM], bf[WTN];
                int c = kk * 4 + l4;
#pragma unroll
                for (int i = 0; i < WTM; ++i) {
                    int m = wm * (WTM * 16) + i * 16 + l15;
                    af[i] = *(const short8*)(As + m * IC + ((c ^ (m & CM)) * 8));
                }
#pragma unroll
                for (int j = 0; j < WTN; ++j) {
                    int m = wn * (WTN * 16) + j * 16 + l15;
                    bf[j] = *(const short8*)(Bs + m * IC + ((c ^ (m & CM)) * 8));
                }
#pragma unroll
                for (int i = 0; i < WTM; ++i)
#pragma unroll
                    for (int j = 0; j < WTN; ++j)
                        acc[i][j] = __builtin_amdgcn_mfma_f32_16x16x32_bf16(
                            af[i], bf[j], acc[i][j], 0, 0, 0);
            }
        }
#pragma unroll
        for (int i = 0; i < WTM; ++i)
#pragma unroll
            for (int j = 0; j < WTN; ++j)
#pragma unroll
                for (int r = 0; r < 4; ++r)
                    mx[i][j][r] = (p == 0) ? acc[i][j][r]
                                           : fmaxf(mx[i][j][r], acc[i][j][r]);
    }

#pragma unroll
    for (int i = 0; i < WTM; ++i) {
        int oc_l = wm * (WTM * 16) + i * 16 + l4 * 4;
#pragma unroll
        for (int j = 0; j < WTN; ++j) {
            int n = n0 + wn * (WTN * 16) + j * 16 + l15;
            ushort_t u[4];
#pragma unroll
            for (int r = 0; r < 4; ++r)
                u[r] = f2bf(fmaxf(mx[i][j][r] + bias[oc_l + r], 0.f));
            if (FC_EPI)
                *(uint2*)(Y + (size_t)n * 2048 + (ph * 4 + pw) * 128 + oc_l) = *(const uint2*)u;
            else
                *(uint2*)(Y + ((size_t)(ph * PW + pw) * 4096 + n) * OC + oc_l) = *(const uint2*)u;
        }
    }
}

// ---------------------------------------------------------------------------
// FC GEMM v3: 64M x 64N tile, BK=64, dbuf -> 32 KB LDS -> 4 blocks/CU (r24).
// ---------------------------------------------------------------------------
template <bool RELU, bool F32OUT>
__global__ __launch_bounds__(256, 4)
void fc_mfma(const ushort_t* __restrict__ A, const ushort_t* __restrict__ BT,
             const float* __restrict__ bias, void* __restrict__ Cout,
             int M, int N, int K) {
    __shared__ ushort_t As[2][64 * 64];
    __shared__ ushort_t Bs[2][64 * 64];
    const int tid = threadIdx.x;
    const int wid = tid >> 6, lane = tid & 63;
    const int wr = wid >> 1, wc = wid & 1;
    const int tm = blockIdx.y * 64, tn = blockIdx.x * 64;
    const int l15 = lane & 15, l4 = lane >> 4;

    f32x4 acc[2][2];
#pragma unroll
    for (int i = 0; i < 2; ++i)
#pragma unroll
        for (int j = 0; j < 2; ++j)
#pragma unroll
            for (int r = 0; r < 4; ++r) acc[i][j][r] = 0.f;

    const int NT = K >> 6;
#pragma unroll
    for (int pass = 0; pass < 2; ++pass) {
        int m = pass * 32 + (tid >> 3);
        int cc = (tid & 7) ^ (m & 7);
        gload_lds16(A + (size_t)(tm + m) * K + cc * 8,
                    &As[0][(pass * 256 + wid * 64) * 8]);
        gload_lds16(BT + (size_t)(tn + m) * K + cc * 8,
                    &Bs[0][(pass * 256 + wid * 64) * 8]);
    }
    __syncthreads();

    for (int t = 0; t < NT; ++t) {
        const int cur = t & 1, nxt = cur ^ 1;
        if (t + 1 < NT) {
            const int k1 = (t + 1) << 6;
#pragma unroll
            for (int pass = 0; pass < 2; ++pass) {
                int m = pass * 32 + (tid >> 3);
                int cc = (tid & 7) ^ (m & 7);
                gload_lds16(A + (size_t)(tm + m) * K + k1 + cc * 8,
                            &As[nxt][(pass * 256 + wid * 64) * 8]);
                gload_lds16(BT + (size_t)(tn + m) * K + k1 + cc * 8,
                            &Bs[nxt][(pass * 256 + wid * 64) * 8]);
            }
        }
#pragma unroll
        for (int kk = 0; kk < 2; ++kk) {
            short8 af[2], bfr[2];
            int c = kk * 4 + l4;
#pragma unroll
            for (int i = 0; i < 2; ++i) {
                int m = wr * 32 + i * 16 + l15;
                af[i] = *(const short8*)(&As[cur][m * 64 + (c ^ (m & 7)) * 8]);
                int nn = wc * 32 + i * 16 + l15;
                bfr[i] = *(const short8*)(&Bs[cur][nn * 64 + (c ^ (nn & 7)) * 8]);
            }
#pragma unroll
            for (int i = 0; i < 2; ++i)
#pragma unroll
                for (int j = 0; j < 2; ++j)
                    acc[i][j] = __builtin_amdgcn_mfma_f32_16x16x32_bf16(
                        af[i], bfr[j], acc[i][j], 0, 0, 0);
        }
        __syncthreads();
    }

#pragma unroll
    for (int i = 0; i < 2; ++i) {
        int row = tm + wr * 32 + i * 16 + l4 * 4;
#pragma unroll
        for (int j = 0; j < 2; ++j) {
            int col = tn + wc * 32 + j * 16 + l15;
            float bv = bias[col];
#pragma unroll
            for (int r = 0; r < 4; ++r) {
                float v = acc[i][j][r] + bv;
                if (RELU) v = fmaxf(v, 0.f);
                if (F32OUT)
                    ((float*)Cout)[(size_t)(row + r) * N + col] = v;
                else
                    ((ushort_t*)Cout)[(size_t)(row + r) * N + col] = f2bf(v);
            }
        }
    }
}

// ---------------------------------------------------------------------------
extern "C" void kernel_launch(void* const* d_in, const int* in_sizes, int n_in,
                              void* d_out, int out_size, void* d_ws, size_t ws_size,
                              hipStream_t stream) {
    const float* x     = (const float*)d_in[0];
    const float* noise = (const float*)d_in[1];
    const float* c1w = (const float*)d_in[2];  const float* c1b = (const float*)d_in[3];
    const float* c2w = (const float*)d_in[4];  const float* c2b = (const float*)d_in[5];
    const float* c3w = (const float*)d_in[6];  const float* c3b = (const float*)d_in[7];
    const float* f1w = (const float*)d_in[8];  const float* f1b = (const float*)d_in[9];
    const float* f2w = (const float*)d_in[10]; const float* f2b = (const float*)d_in[11];
    const float* f3w = (const float*)d_in[12]; const float* f3b = (const float*)d_in[13];
    const float* f4w = (const float*)d_in[14]; const float* f4b = (const float*)d_in[15];
    const float* f5w = (const float*)d_in[16]; const float* f5b = (const float*)d_in[17];
    float* out = (float*)d_out;

    char* ws = (char*)d_ws;
    const size_t MB = 1ull << 20;
    int*      ids  = (int*)ws;                               // 256 KB
    ushort_t* wc1  = (ushort_t*)(ws + 1 * MB);               // 6 KB
    ushort_t* wc2  = (ushort_t*)(ws + 1 * MB + 64 * 1024);   // 36 KB
    ushort_t* wc3  = (ushort_t*)(ws + 1 * MB + 128 * 1024);  // 144 KB
    ushort_t* wf1  = (ushort_t*)(ws + 2 * MB);               // 4 MB
    ushort_t* wf2  = (ushort_t*)(ws + 6 * MB);               // 2 MB
    ushort_t* wf3  = (ushort_t*)(ws + 8 * MB);               // 2 MB
    ushort_t* wf4  = (ushort_t*)(ws + 10 * MB);              // 2 MB
    ushort_t* wf5  = (ushort_t*)(ws + 12 * MB);              // 0.5 MB
    ushort_t* act1 = (ushort_t*)(ws + 89 * MB);              // 64 MB  [256pos][4096n][32oc]
    ushort_t* act2 = (ushort_t*)(ws + 153 * MB);             // 32 MB  [64pos][4096n][64oc]
    ushort_t* act3 = (ushort_t*)(ws + 185 * MB);             // 16 MB  [4096][2048]
    ushort_t* fcb1 = (ushort_t*)(ws + 201 * MB);             // 8 MB
    ushort_t* fcb2 = (ushort_t*)(ws + 209 * MB);             // 8 MB

    // all weight preps in one launch
    prep_all<<<dim3(5748), 256, 0, stream>>>(c1w, c2w, c3w, f1w, f2w, f3w, f4w, f5w,
                                             wc1, wc2, wc3, wf1, wf2, wf3, wf4, wf5);

    // rank + fused shuffle/conv1 (XCD-chunked grid)
    rank_kernel<<<BATCH / 256, 256, 0, stream>>>(noise, ids, out + (size_t)BATCH * 256);
    shuffle_conv1<<<dim3(2048), 256, 0, stream>>>(x, ids, wc1, c1b, act1);

    // conv2 / conv3
    conv2_gemm<<<dim3(4096), 256, 0, stream>>>(act1, wc2, c2b, act2);
    conv_gemm<64, 8, 128, true, 2><<<dim3(512), 256, 0, stream>>>(act2, wc3, c3b, act3);

    // FC chain (64x64 tiles, 4 blocks/CU)
    fc_mfma<true,  false><<<dim3(16, 64), 256, 0, stream>>>(act3, wf1, f1b, fcb1, BATCH, 1024, 2048);
    fc_mfma<true,  false><<<dim3(16, 64), 256, 0, stream>>>(fcb1, wf2, f2b, fcb2, BATCH, 1024, 1024);
    fc_mfma<true,  false><<<dim3(16, 64), 256, 0, stream>>>(fcb2, wf3, f3b, fcb1, BATCH, 1024, 1024);
    fc_mfma<true,  false><<<dim3(16, 64), 256, 0, stream>>>(fcb1, wf4, f4b, fcb2, BATCH, 1024, 1024);
    fc_mfma<false, true ><<<dim3(4, 64),  256, 0, stream>>>(fcb2, wf5, f5b, out, BATCH, 256, 1024);
}